// Round 1
// baseline (127.932 us; speedup 1.0000x reference)
//
#include <hip/hip_runtime.h>
#include <math.h>

// Problem constants (from reference setup_inputs)
#define B_   2
#define C_   32
#define H_   176
#define W_   608
#define HO_  351    // (H-1)*2 - 2*1 + 3 = 351
#define WO_  1215   // (W-1)*2 - 2*1 + 3 = 1215
#define EPS_ 1e-20f

// Tile config
#define TOH 32      // output tile rows
#define TOW 128     // output tile cols
#define NIH 17      // input tile rows  = TOH/2 + 1
#define NIW 65      // input tile cols  = TOW/2 + 1
#define NTHREADS 256

__device__ __forceinline__ float softplus_f(float x) {
    // numerically stable softplus, matches jax.nn.softplus closely
    return fmaxf(x, 0.0f) + log1pf(expf(-fabsf(x)));
}

extern "C" __global__ __launch_bounds__(NTHREADS)
void structn_deconv_fused(const float* __restrict__ d,
                          const float* __restrict__ cd,
                          const float* __restrict__ gy,
                          const float* __restrict__ cgy,
                          const float* __restrict__ wpr,   // (1,C,1,1)
                          const float* __restrict__ swr,   // (C,1,3,3)
                          const float* __restrict__ bias,  // (1,C,1,1)
                          float* __restrict__ out)         // [2][B][C][HO][WO]
{
    __shared__ float s_ngy[NIH * NIW];   // cgy_f * gy_f  at input pixel
    __shared__ float s_cgf[NIH * NIW];   // cgy_f         at input pixel

    const int plane = blockIdx.z;            // b*C + c
    const int c     = plane & (C_ - 1);
    const int oy0   = blockIdx.y * TOH;
    const int ox0   = blockIdx.x * TOW;
    const int t     = threadIdx.x;

    // ---- per-channel constants (recomputed per thread; trivial cost) ----
    const float wp      = softplus_f(wpr[c]);
    const float inv_wp1 = 1.0f / (wp + 1.0f);
    const float bv      = bias[c];
    float sw[9];
#pragma unroll
    for (int k = 0; k < 9; ++k) sw[k] = softplus_f(swr[c * 9 + k]);
    // cdenom = convT(ones): all taps always valid (Ho=2H-1, Wo=2W-1),
    // so it depends only on output parity.
    const float cden_ee = sw[4];
    const float cden_eo = sw[3] + sw[5];
    const float cden_oe = sw[1] + sw[7];
    const float cden_oo = sw[0] + sw[2] + sw[6] + sw[8];

    const int ih0 = oy0 >> 1;
    const int iw0 = ox0 >> 1;

    const size_t pbase = (size_t)plane * (H_ * W_);
    const float* __restrict__ dP  = d   + pbase;
    const float* __restrict__ cdP = cd  + pbase;
    const float* __restrict__ gyP = gy  + pbase;
    const float* __restrict__ cgP = cgy + pbase;

    // ---- stage fused input-pixel values into LDS ----
    for (int idx = t; idx < NIH * NIW; idx += NTHREADS) {
        const int r   = idx / NIW;
        const int col = idx - r * NIW;
        const int ih  = ih0 + r;
        const int iw  = iw0 + col;
        float ngy_v = 0.0f, cgf_v = 0.0f;
        if (ih < H_ && iw < W_) {
            const int up = (ih == 0)      ? (H_ - 1) : ih - 1;  // roll wraps d
            const int dn = (ih == H_ - 1) ? 0        : ih + 1;
            const float d_up  = dP[(size_t)up * W_ + iw];
            const float d_dn  = dP[(size_t)dn * W_ + iw];
            const float cd_up = (ih == 0)      ? 0.0f : cdP[(size_t)(ih - 1) * W_ + iw];
            const float cd_dn = (ih == H_ - 1) ? 0.0f : cdP[(size_t)(ih + 1) * W_ + iw];
            const float g  = gyP[(size_t)ih * W_ + iw];
            const float cg = cgP[(size_t)ih * W_ + iw];

            const float cfd    = cd_up * cd_up;                       // cgy_from_ds
            const float height = (cd_up * d_up + cd_dn * d_dn) / (cd_up + cd_dn);
            const float gfd    = ((d_dn - d_up) * 0.5f) / height;     // gy_from_ds
            const float num    = wp * cg * g + cfd * gfd;
            const float den    = wp * cg + cfd;
            // cgy_f = den/(wp+1); cgy_f*gy_f = num/(wp+1)
            ngy_v = num * inv_wp1;
            cgf_v = den * inv_wp1;
        }
        s_ngy[idx] = ngy_v;
        s_cgf[idx] = cgf_v;
    }
    __syncthreads();

    // ---- consume: one 2x2 output quad per thread per iter ----
    float* __restrict__ out0 = out + (size_t)plane * (HO_ * WO_);
    float* __restrict__ out1 = out + (size_t)(B_ * C_) * (HO_ * WO_)
                                   + (size_t)plane * (HO_ * WO_);

#pragma unroll
    for (int iter = 0; iter < 4; ++iter) {
        const int qy = (t >> 6) + iter * 4;   // 16 quad rows total
        const int qx = t & 63;                // 64 quad cols
        const int oy = oy0 + 2 * qy;
        const int ox = ox0 + 2 * qx;
        if (oy >= HO_ || ox >= WO_) continue;

        const int l0 = qy * NIW + qx;
        const float n00 = s_ngy[l0],           c00 = s_cgf[l0];
        const float n01 = s_ngy[l0 + 1],       c01 = s_cgf[l0 + 1];
        const float n10 = s_ngy[l0 + NIW],     c10 = s_cgf[l0 + NIW];
        const float n11 = s_ngy[l0 + NIW + 1], c11 = s_cgf[l0 + NIW + 1];

        const size_t o00 = (size_t)oy * WO_ + ox;
        const bool xok = (ox + 1 < WO_);
        const bool yok = (oy + 1 < HO_);

        // (even, even): tap (i,j) * sw[1][1]
        {
            const float nom = n00 * sw[4];
            const float den = c00 * sw[4];
            out0[o00] = ((nom / (den + EPS_) + bv) + bv) * 0.5f;
            out1[o00] = den / (cden_ee + EPS_);
        }
        // (even, odd): (i,j)*sw[1][2] + (i,j+1)*sw[1][0]
        if (xok) {
            const float nom = n00 * sw[5] + n01 * sw[3];
            const float den = c00 * sw[5] + c01 * sw[3];
            out0[o00 + 1] = ((nom / (den + EPS_) + bv) + bv) * 0.5f;
            out1[o00 + 1] = den / (cden_eo + EPS_);
        }
        // (odd, even): (i,j)*sw[2][1] + (i+1,j)*sw[0][1]
        if (yok) {
            const float nom = n00 * sw[7] + n10 * sw[1];
            const float den = c00 * sw[7] + c10 * sw[1];
            out0[o00 + WO_] = ((nom / (den + EPS_) + bv) + bv) * 0.5f;
            out1[o00 + WO_] = den / (cden_oe + EPS_);
        }
        // (odd, odd): (i,j)*sw[2][2] + (i,j+1)*sw[2][0] + (i+1,j)*sw[0][2] + (i+1,j+1)*sw[0][0]
        if (xok && yok) {
            const float nom = n00 * sw[8] + n01 * sw[6] + n10 * sw[2] + n11 * sw[0];
            const float den = c00 * sw[8] + c01 * sw[6] + c10 * sw[2] + c11 * sw[0];
            out0[o00 + WO_ + 1] = ((nom / (den + EPS_) + bv) + bv) * 0.5f;
            out1[o00 + WO_ + 1] = den / (cden_oo + EPS_);
        }
    }
}

extern "C" void kernel_launch(void* const* d_in, const int* in_sizes, int n_in,
                              void* d_out, int out_size, void* d_ws, size_t ws_size,
                              hipStream_t stream) {
    const float* d    = (const float*)d_in[0];
    const float* cd   = (const float*)d_in[1];
    const float* gy   = (const float*)d_in[2];
    const float* cgy  = (const float*)d_in[3];
    const float* wpr  = (const float*)d_in[4];
    const float* swr  = (const float*)d_in[5];
    const float* bias = (const float*)d_in[6];
    float* out = (float*)d_out;

    dim3 grid((WO_ + TOW - 1) / TOW,   // 10
              (HO_ + TOH - 1) / TOH,   // 11
              B_ * C_);                // 64
    structn_deconv_fused<<<grid, NTHREADS, 0, stream>>>(d, cd, gy, cgy, wpr, swr, bias, out);
}

// Round 2
// 123.679 us; speedup vs baseline: 1.0344x; 1.0344x over previous
//
#include <hip/hip_runtime.h>
#include <math.h>

// Problem constants (from reference setup_inputs)
#define B_   2
#define C_   32
#define H_   176
#define W_   608
#define HO_  351    // (H-1)*2 - 2*1 + 3
#define WO_  1215   // (W-1)*2 - 2*1 + 3
#define EPS_ 1e-20f

// Tile config
#define TOH 32      // output tile rows
#define TOW 128     // output tile cols
#define NIH 17      // input tile rows  = TOH/2 + 1
#define NIW 65      // input tile cols  = TOW/2 + 1
#define NTHREADS 256
#define CSTRIDE 16  // floats per channel in the const table

__device__ __forceinline__ float softplus_f(float x) {
    return fmaxf(x, 0.0f) + log1pf(expf(-fabsf(x)));
}

// ---- per-channel constants, computed ONCE (not per block/thread) ----
// layout per channel (CSTRIDE floats):
//  [0..8]  softplus(sw[k])
//  [9]     wp = softplus(wpr)
//  [10]    1/(wp+1)
//  [11]    bias
//  [12..15] 1/(cdenom_parity + EPS): ee, eo, oe, oo
extern "C" __global__ void precompute_consts(const float* __restrict__ wpr,
                                             const float* __restrict__ swr,
                                             const float* __restrict__ bias,
                                             float* __restrict__ cc)
{
    const int c = threadIdx.x;
    if (c >= C_) return;
    float sw[9];
#pragma unroll
    for (int k = 0; k < 9; ++k) sw[k] = softplus_f(swr[c * 9 + k]);
    const float wp = softplus_f(wpr[c]);
    float* o = cc + c * CSTRIDE;
#pragma unroll
    for (int k = 0; k < 9; ++k) o[k] = sw[k];
    o[9]  = wp;
    o[10] = 1.0f / (wp + 1.0f);
    o[11] = bias[c];
    o[12] = 1.0f / (sw[4] + EPS_);
    o[13] = 1.0f / (sw[3] + sw[5] + EPS_);
    o[14] = 1.0f / (sw[1] + sw[7] + EPS_);
    o[15] = 1.0f / (sw[0] + sw[2] + sw[6] + sw[8] + EPS_);
}

extern "C" __global__ __launch_bounds__(NTHREADS)
void structn_deconv_fused(const float* __restrict__ d,
                          const float* __restrict__ cd,
                          const float* __restrict__ gy,
                          const float* __restrict__ cgy,
                          const float* __restrict__ cc,    // const table
                          float* __restrict__ out)         // [2][B][C][HO][WO]
{
    __shared__ float s_ngy[NIH * NIW];   // (cgy_f * gy_f) at input pixel
    __shared__ float s_cgf[NIH * NIW];   // cgy_f          at input pixel

    const int plane = blockIdx.z;            // b*C + c
    const int c     = plane & (C_ - 1);
    const int oy0   = blockIdx.y * TOH;
    const int ox0   = blockIdx.x * TOW;
    const int t     = threadIdx.x;

    // wave-uniform scalar loads of precomputed constants
    const float* __restrict__ ch = cc + c * CSTRIDE;
    const float sw0 = ch[0], sw1 = ch[1], sw2 = ch[2];
    const float sw3 = ch[3], sw4 = ch[4], sw5 = ch[5];
    const float sw6 = ch[6], sw7 = ch[7], sw8 = ch[8];
    const float wp      = ch[9];
    const float inv_wp1 = ch[10];
    const float bv      = ch[11];
    const float icd_ee  = ch[12];
    const float icd_eo  = ch[13];
    const float icd_oe  = ch[14];
    const float icd_oo  = ch[15];

    const int ih0 = oy0 >> 1;
    const int iw0 = ox0 >> 1;

    const int pbase = plane * (H_ * W_);
    const float* __restrict__ dP  = d   + pbase;
    const float* __restrict__ cdP = cd  + pbase;
    const float* __restrict__ gyP = gy  + pbase;
    const float* __restrict__ cgP = cgy + pbase;

    // ---- stage fused input-pixel values into LDS ----
    for (int idx = t; idx < NIH * NIW; idx += NTHREADS) {
        const int r   = idx / NIW;
        const int col = idx - r * NIW;
        const int ih  = ih0 + r;
        const int iw  = iw0 + col;
        float ngy_v = 0.0f, cgf_v = 0.0f;
        if (ih < H_ && iw < W_) {
            const int up = (ih == 0)      ? (H_ - 1) : ih - 1;  // roll wraps d
            const int dn = (ih == H_ - 1) ? 0        : ih + 1;
            const float d_up  = dP[up * W_ + iw];
            const float d_dn  = dP[dn * W_ + iw];
            const float cd_up = (ih == 0)      ? 0.0f : cdP[(ih - 1) * W_ + iw];
            const float cd_dn = (ih == H_ - 1) ? 0.0f : cdP[(ih + 1) * W_ + iw];
            const float g  = gyP[ih * W_ + iw];
            const float cg = cgP[ih * W_ + iw];

            const float cfd = cd_up * cd_up;                     // cgy_from_ds
            // gfd = 0.5*(d_dn-d_up)/height, height = (cu*du+cn*dn)/(cu+cn)
            //     = 0.5*(d_dn-d_up)*(cu+cn) / (cu*du+cn*dn)
            const float rs  = __builtin_amdgcn_rcpf(cd_up * d_up + cd_dn * d_dn);
            const float gfd = 0.5f * (d_dn - d_up) * (cd_up + cd_dn) * rs;
            const float num = wp * cg * g + cfd * gfd;
            const float den = wp * cg + cfd;
            ngy_v = num * inv_wp1;       // cgy_f * gy_f
            cgf_v = den * inv_wp1;       // cgy_f
        }
        s_ngy[idx] = ngy_v;
        s_cgf[idx] = cgf_v;
    }
    __syncthreads();

    // ---- consume: one 2x2 output quad per thread per iter ----
    float* __restrict__ out0 = out + plane * (HO_ * WO_);
    float* __restrict__ out1 = out + (B_ * C_) * (HO_ * WO_) + plane * (HO_ * WO_);

#pragma unroll
    for (int iter = 0; iter < 4; ++iter) {
        const int qy = (t >> 6) + iter * 4;   // 16 quad rows total
        const int qx = t & 63;                // 64 quad cols
        const int oy = oy0 + 2 * qy;
        const int ox = ox0 + 2 * qx;
        if (oy >= HO_ || ox >= WO_) continue;

        const int l0 = qy * NIW + qx;
        const float n00 = s_ngy[l0],           c00 = s_cgf[l0];
        const float n01 = s_ngy[l0 + 1],       c01 = s_cgf[l0 + 1];
        const float n10 = s_ngy[l0 + NIW],     c10 = s_cgf[l0 + NIW];
        const float n11 = s_ngy[l0 + NIW + 1], c11 = s_cgf[l0 + NIW + 1];

        const int o00 = oy * WO_ + ox;
        const bool xok = (ox + 1 < WO_);
        const bool yok = (oy + 1 < HO_);

        // (even,even): tap sw[1][1]
        {
            const float nom = n00 * sw4;
            const float den = c00 * sw4;
            const float r   = __builtin_amdgcn_rcpf(den + EPS_);
            out0[o00] = fmaf(0.5f * nom, r, bv);
            out1[o00] = den * icd_ee;
        }
        // (even,odd): (i,j)*sw[1][2] + (i,j+1)*sw[1][0]
        if (xok) {
            const float nom = n00 * sw5 + n01 * sw3;
            const float den = c00 * sw5 + c01 * sw3;
            const float r   = __builtin_amdgcn_rcpf(den + EPS_);
            out0[o00 + 1] = fmaf(0.5f * nom, r, bv);
            out1[o00 + 1] = den * icd_eo;
        }
        // (odd,even): (i,j)*sw[2][1] + (i+1,j)*sw[0][1]
        if (yok) {
            const float nom = n00 * sw7 + n10 * sw1;
            const float den = c00 * sw7 + c10 * sw1;
            const float r   = __builtin_amdgcn_rcpf(den + EPS_);
            out0[o00 + WO_] = fmaf(0.5f * nom, r, bv);
            out1[o00 + WO_] = den * icd_oe;
        }
        // (odd,odd): (i,j)*sw[2][2] + (i,j+1)*sw[2][0] + (i+1,j)*sw[0][2] + (i+1,j+1)*sw[0][0]
        if (xok && yok) {
            const float nom = n00 * sw8 + n01 * sw6 + n10 * sw2 + n11 * sw0;
            const float den = c00 * sw8 + c01 * sw6 + c10 * sw2 + c11 * sw0;
            const float r   = __builtin_amdgcn_rcpf(den + EPS_);
            out0[o00 + WO_ + 1] = fmaf(0.5f * nom, r, bv);
            out1[o00 + WO_ + 1] = den * icd_oo;
        }
    }
}

extern "C" void kernel_launch(void* const* d_in, const int* in_sizes, int n_in,
                              void* d_out, int out_size, void* d_ws, size_t ws_size,
                              hipStream_t stream) {
    const float* d    = (const float*)d_in[0];
    const float* cd   = (const float*)d_in[1];
    const float* gy   = (const float*)d_in[2];
    const float* cgy  = (const float*)d_in[3];
    const float* wpr  = (const float*)d_in[4];
    const float* swr  = (const float*)d_in[5];
    const float* bias = (const float*)d_in[6];
    float* out = (float*)d_out;
    float* cc  = (float*)d_ws;   // 32*16 floats = 2 KiB of scratch

    precompute_consts<<<1, 64, 0, stream>>>(wpr, swr, bias, cc);

    dim3 grid((WO_ + TOW - 1) / TOW,   // 10
              (HO_ + TOH - 1) / TOH,   // 11
              B_ * C_);                // 64
    structn_deconv_fused<<<grid, NTHREADS, 0, stream>>>(d, cd, gy, cgy, cc, out);
}

// Round 3
// 114.628 us; speedup vs baseline: 1.1161x; 1.0790x over previous
//
#include <hip/hip_runtime.h>
#include <math.h>

// Problem constants
#define B_   2
#define C_   32
#define H_   176
#define W_   608
#define HO_  351
#define WO_  1215
#define EPS_ 1e-20f

// Tile config
#define TOH 32
#define TOW 128
#define NIH 17      // input tile rows  = TOH/2 + 1
#define NIW 65      // input tile cols  = TOW/2 + 1
#define LDW 66      // padded LDS row stride
#define NTHREADS 256
#define CSTRIDE 16

typedef float f4_t __attribute__((ext_vector_type(4)));
typedef f4_t uf4 __attribute__((aligned(4)));   // may be 4B-aligned (WO_ odd)

__device__ __forceinline__ void store4(float* p, f4_t v) { *(uf4*)p = v; }

__device__ __forceinline__ float softplus_f(float x) {
    return fmaxf(x, 0.0f) + log1pf(expf(-fabsf(x)));
}

// per-channel constants: [0..8] softplus(sw), [9] wp, [10] 1/(wp+1), [11] bias,
// [12..15] 1/(cdenom_parity+EPS): ee, eo, oe, oo
extern "C" __global__ void precompute_consts(const float* __restrict__ wpr,
                                             const float* __restrict__ swr,
                                             const float* __restrict__ bias,
                                             float* __restrict__ cc)
{
    const int c = threadIdx.x;
    if (c >= C_) return;
    float sw[9];
#pragma unroll
    for (int k = 0; k < 9; ++k) sw[k] = softplus_f(swr[c * 9 + k]);
    const float wp = softplus_f(wpr[c]);
    float* o = cc + c * CSTRIDE;
#pragma unroll
    for (int k = 0; k < 9; ++k) o[k] = sw[k];
    o[9]  = wp;
    o[10] = 1.0f / (wp + 1.0f);
    o[11] = bias[c];
    o[12] = 1.0f / (sw[4] + EPS_);
    o[13] = 1.0f / (sw[3] + sw[5] + EPS_);
    o[14] = 1.0f / (sw[1] + sw[7] + EPS_);
    o[15] = 1.0f / (sw[0] + sw[2] + sw[6] + sw[8] + EPS_);
}

extern "C" __global__ __launch_bounds__(NTHREADS)
void structn_deconv_fused(const float* __restrict__ d,
                          const float* __restrict__ cd,
                          const float* __restrict__ gy,
                          const float* __restrict__ cgy,
                          const float* __restrict__ cc,
                          float* __restrict__ out)
{
    __shared__ float s_ngy[NIH * LDW];
    __shared__ float s_cgf[NIH * LDW];

    const int plane = blockIdx.z;
    const int c     = plane & (C_ - 1);
    const int bx    = blockIdx.x;
    const int by    = blockIdx.y;
    const int oy0   = by * TOH;
    const int ox0   = bx * TOW;
    const int t     = threadIdx.x;

    const float* __restrict__ ch = cc + c * CSTRIDE;
    const float sw0 = ch[0], sw1 = ch[1], sw2 = ch[2];
    const float sw3 = ch[3], sw4 = ch[4], sw5 = ch[5];
    const float sw6 = ch[6], sw7 = ch[7], sw8 = ch[8];
    const float wp      = ch[9];
    const float inv_wp1 = ch[10];
    const float bv      = ch[11];
    const float icd_ee  = ch[12];
    const float icd_eo  = ch[13];
    const float icd_oe  = ch[14];
    const float icd_oo  = ch[15];

    const int ih0 = oy0 >> 1;
    const int iw0 = ox0 >> 1;

    const int pbase = plane * (H_ * W_);
    const float* __restrict__ dP  = d   + pbase;
    const float* __restrict__ cdP = cd  + pbase;
    const float* __restrict__ gyP = gy  + pbase;
    const float* __restrict__ cgP = cgy + pbase;

    float* __restrict__ out0 = out + plane * (HO_ * WO_);
    float* __restrict__ out1 = out + (B_ * C_) * (HO_ * WO_) + plane * (HO_ * WO_);

    const bool interior = (bx <= 8) & (by >= 1) & (by <= 9);

    if (interior) {
        // ---------- interior: no bounds checks, no wrap ----------
        // stage: 33 col-pairs x 17 rows = 561 float2 items
        for (int idx = t; idx < 33 * NIH; idx += NTHREADS) {
            const int r  = idx / 33;
            const int cp = idx - r * 33;
            const int ih = ih0 + r;          // 16..160
            const int iw = iw0 + 2 * cp;     // <= 576 (+1 -> 577 < 608)
            const int ro = ih * W_ + iw;
            const float2 du = *(const float2*)(dP  + ro - W_);
            const float2 dn = *(const float2*)(dP  + ro + W_);
            const float2 cu = *(const float2*)(cdP + ro - W_);
            const float2 cn = *(const float2*)(cdP + ro + W_);
            const float2 g  = *(const float2*)(gyP + ro);
            const float2 cg = *(const float2*)(cgP + ro);

            float2 ngy2, cgf2;
            {
                const float cfd = cu.x * cu.x;
                const float rs  = __builtin_amdgcn_rcpf(cu.x * du.x + cn.x * dn.x);
                const float gfd = 0.5f * (dn.x - du.x) * (cu.x + cn.x) * rs;
                const float num = wp * cg.x * g.x + cfd * gfd;
                const float den = wp * cg.x + cfd;
                ngy2.x = num * inv_wp1;
                cgf2.x = den * inv_wp1;
            }
            {
                const float cfd = cu.y * cu.y;
                const float rs  = __builtin_amdgcn_rcpf(cu.y * du.y + cn.y * dn.y);
                const float gfd = 0.5f * (dn.y - du.y) * (cu.y + cn.y) * rs;
                const float num = wp * cg.y * g.y + cfd * gfd;
                const float den = wp * cg.y + cfd;
                ngy2.y = num * inv_wp1;
                cgf2.y = den * inv_wp1;
            }
            const int lo = r * LDW + 2 * cp;
            *(float2*)(s_ngy + lo) = ngy2;
            *(float2*)(s_cgf + lo) = cgf2;
        }
        __syncthreads();

        // consume: 2x4 output patch per thread, 2 iterations
#pragma unroll
        for (int it2 = 0; it2 < 2; ++it2) {
            const int qy  = (t >> 5) + it2 * 8;   // 0..15
            const int dqx = t & 31;
            const int c0  = 2 * dqx;
            const int lb  = qy * LDW + c0;

            const float n00 = s_ngy[lb],       n01 = s_ngy[lb + 1],       n02 = s_ngy[lb + 2];
            const float n10 = s_ngy[lb + LDW], n11 = s_ngy[lb + LDW + 1], n12 = s_ngy[lb + LDW + 2];
            const float c00 = s_cgf[lb],       c01 = s_cgf[lb + 1],       c02 = s_cgf[lb + 2];
            const float c10 = s_cgf[lb + LDW], c11 = s_cgf[lb + LDW + 1], c12 = s_cgf[lb + LDW + 2];

            // even output row: ee, eo, ee, eo
            const float dE0 = c00 * sw4;
            const float nE0 = n00 * sw4;
            const float dE1 = c00 * sw5 + c01 * sw3;
            const float nE1 = n00 * sw5 + n01 * sw3;
            const float dE2 = c01 * sw4;
            const float nE2 = n01 * sw4;
            const float dE3 = c01 * sw5 + c02 * sw3;
            const float nE3 = n01 * sw5 + n02 * sw3;
            // odd output row: oe, oo, oe, oo
            const float dO0 = c00 * sw7 + c10 * sw1;
            const float nO0 = n00 * sw7 + n10 * sw1;
            const float dO1 = c00 * sw8 + c01 * sw6 + c10 * sw2 + c11 * sw0;
            const float nO1 = n00 * sw8 + n01 * sw6 + n10 * sw2 + n11 * sw0;
            const float dO2 = c01 * sw7 + c11 * sw1;
            const float nO2 = n01 * sw7 + n11 * sw1;
            const float dO3 = c01 * sw8 + c02 * sw6 + c11 * sw2 + c12 * sw0;
            const float nO3 = n01 * sw8 + n02 * sw6 + n11 * sw2 + n12 * sw0;

            f4_t g0, g1, q0, q1;
            g0.x = fmaf(0.5f * nE0, __builtin_amdgcn_rcpf(dE0 + EPS_), bv);
            g0.y = fmaf(0.5f * nE1, __builtin_amdgcn_rcpf(dE1 + EPS_), bv);
            g0.z = fmaf(0.5f * nE2, __builtin_amdgcn_rcpf(dE2 + EPS_), bv);
            g0.w = fmaf(0.5f * nE3, __builtin_amdgcn_rcpf(dE3 + EPS_), bv);
            g1.x = fmaf(0.5f * nO0, __builtin_amdgcn_rcpf(dO0 + EPS_), bv);
            g1.y = fmaf(0.5f * nO1, __builtin_amdgcn_rcpf(dO1 + EPS_), bv);
            g1.z = fmaf(0.5f * nO2, __builtin_amdgcn_rcpf(dO2 + EPS_), bv);
            g1.w = fmaf(0.5f * nO3, __builtin_amdgcn_rcpf(dO3 + EPS_), bv);
            q0.x = dE0 * icd_ee;  q0.y = dE1 * icd_eo;
            q0.z = dE2 * icd_ee;  q0.w = dE3 * icd_eo;
            q1.x = dO0 * icd_oe;  q1.y = dO1 * icd_oo;
            q1.z = dO2 * icd_oe;  q1.w = dO3 * icd_oo;

            const int oy = oy0 + 2 * qy;
            const int ox = ox0 + 4 * dqx;
            const int o00 = oy * WO_ + ox;
            store4(out0 + o00,       g0);
            store4(out0 + o00 + WO_, g1);
            store4(out1 + o00,       q0);
            store4(out1 + o00 + WO_, q1);
        }
    } else {
        // ---------- edge path: guarded scalar (round-2 logic) ----------
        for (int idx = t; idx < NIH * NIW; idx += NTHREADS) {
            const int r   = idx / NIW;
            const int col = idx - r * NIW;
            const int ih  = ih0 + r;
            const int iw  = iw0 + col;
            float ngy_v = 0.0f, cgf_v = 0.0f;
            if (ih < H_ && iw < W_) {
                const int up = (ih == 0)      ? (H_ - 1) : ih - 1;
                const int dn = (ih == H_ - 1) ? 0        : ih + 1;
                const float d_up  = dP[up * W_ + iw];
                const float d_dn  = dP[dn * W_ + iw];
                const float cd_up = (ih == 0)      ? 0.0f : cdP[(ih - 1) * W_ + iw];
                const float cd_dn = (ih == H_ - 1) ? 0.0f : cdP[(ih + 1) * W_ + iw];
                const float g  = gyP[ih * W_ + iw];
                const float cg = cgP[ih * W_ + iw];

                const float cfd = cd_up * cd_up;
                const float rs  = __builtin_amdgcn_rcpf(cd_up * d_up + cd_dn * d_dn);
                const float gfd = 0.5f * (d_dn - d_up) * (cd_up + cd_dn) * rs;
                const float num = wp * cg * g + cfd * gfd;
                const float den = wp * cg + cfd;
                ngy_v = num * inv_wp1;
                cgf_v = den * inv_wp1;
            }
            s_ngy[r * LDW + col] = ngy_v;
            s_cgf[r * LDW + col] = cgf_v;
        }
        __syncthreads();

#pragma unroll
        for (int iter = 0; iter < 4; ++iter) {
            const int qy = (t >> 6) + iter * 4;
            const int qx = t & 63;
            const int oy = oy0 + 2 * qy;
            const int ox = ox0 + 2 * qx;
            if (oy >= HO_ || ox >= WO_) continue;

            const int l0 = qy * LDW + qx;
            const float n00 = s_ngy[l0],           c00 = s_cgf[l0];
            const float n01 = s_ngy[l0 + 1],       c01 = s_cgf[l0 + 1];
            const float n10 = s_ngy[l0 + LDW],     c10 = s_cgf[l0 + LDW];
            const float n11 = s_ngy[l0 + LDW + 1], c11 = s_cgf[l0 + LDW + 1];

            const int o00 = oy * WO_ + ox;
            const bool xok = (ox + 1 < WO_);
            const bool yok = (oy + 1 < HO_);

            {
                const float den = c00 * sw4;
                const float r   = __builtin_amdgcn_rcpf(den + EPS_);
                out0[o00] = fmaf(0.5f * (n00 * sw4), r, bv);
                out1[o00] = den * icd_ee;
            }
            if (xok) {
                const float nom = n00 * sw5 + n01 * sw3;
                const float den = c00 * sw5 + c01 * sw3;
                const float r   = __builtin_amdgcn_rcpf(den + EPS_);
                out0[o00 + 1] = fmaf(0.5f * nom, r, bv);
                out1[o00 + 1] = den * icd_eo;
            }
            if (yok) {
                const float nom = n00 * sw7 + n10 * sw1;
                const float den = c00 * sw7 + c10 * sw1;
                const float r   = __builtin_amdgcn_rcpf(den + EPS_);
                out0[o00 + WO_] = fmaf(0.5f * nom, r, bv);
                out1[o00 + WO_] = den * icd_oe;
            }
            if (xok && yok) {
                const float nom = n00 * sw8 + n01 * sw6 + n10 * sw2 + n11 * sw0;
                const float den = c00 * sw8 + c01 * sw6 + c10 * sw2 + c11 * sw0;
                const float r   = __builtin_amdgcn_rcpf(den + EPS_);
                out0[o00 + WO_ + 1] = fmaf(0.5f * nom, r, bv);
                out1[o00 + WO_ + 1] = den * icd_oo;
            }
        }
    }
}

extern "C" void kernel_launch(void* const* d_in, const int* in_sizes, int n_in,
                              void* d_out, int out_size, void* d_ws, size_t ws_size,
                              hipStream_t stream) {
    const float* d    = (const float*)d_in[0];
    const float* cd   = (const float*)d_in[1];
    const float* gy   = (const float*)d_in[2];
    const float* cgy  = (const float*)d_in[3];
    const float* wpr  = (const float*)d_in[4];
    const float* swr  = (const float*)d_in[5];
    const float* bias = (const float*)d_in[6];
    float* out = (float*)d_out;
    float* cc  = (float*)d_ws;   // 2 KiB scratch

    precompute_consts<<<1, 64, 0, stream>>>(wpr, swr, bias, cc);

    dim3 grid((WO_ + TOW - 1) / TOW,   // 10
              (HO_ + TOH - 1) / TOH,   // 11
              B_ * C_);                // 64
    structn_deconv_fused<<<grid, NTHREADS, 0, stream>>>(d, cd, gy, cgy, cc, out);
}

// Round 4
// 85.771 us; speedup vs baseline: 1.4915x; 1.3364x over previous
//
#include <hip/hip_runtime.h>
#include <math.h>

// Problem constants
#define B_   2
#define C_   32
#define H_   176
#define W_   608
#define HO_  351
#define WO_  1215
#define PLANE_O (HO_ * WO_)        // 426465
#define OUT1_O  (B_ * C_ * PLANE_O)// 27293760 (multiple of 4 -> same alignment)
#define EPS_ 1e-20f
#define NTH  512
#define CSTRIDE 16
#define W4   (W_ / 4)              // 152 float4 per input row

typedef float f4_t __attribute__((ext_vector_type(4)));

__device__ __forceinline__ float softplus_f(float x) {
    return fmaxf(x, 0.0f) + log1pf(expf(-fabsf(x)));
}

// per-channel constants: [0..8] softplus(sw), [9] wp, [10] 1/(wp+1), [11] bias,
// [12..15] 1/(cdenom_parity+EPS): ee, eo, oe, oo
extern "C" __global__ void precompute_consts(const float* __restrict__ wpr,
                                             const float* __restrict__ swr,
                                             const float* __restrict__ bias,
                                             float* __restrict__ cc)
{
    const int c = threadIdx.x;
    if (c >= C_) return;
    float sw[9];
#pragma unroll
    for (int k = 0; k < 9; ++k) sw[k] = softplus_f(swr[c * 9 + k]);
    const float wp = softplus_f(wpr[c]);
    float* o = cc + c * CSTRIDE;
#pragma unroll
    for (int k = 0; k < 9; ++k) o[k] = sw[k];
    o[9]  = wp;
    o[10] = 1.0f / (wp + 1.0f);
    o[11] = bias[c];
    o[12] = 1.0f / (sw[4] + EPS_);
    o[13] = 1.0f / (sw[3] + sw[5] + EPS_);
    o[14] = 1.0f / (sw[1] + sw[7] + EPS_);
    o[15] = 1.0f / (sw[0] + sw[2] + sw[6] + sw[8] + EPS_);
}

// Row-based kernel: block = (plane, group of 8 output rows), 8 waves,
// wave w owns output row oy = g*8 + w (parity = w&1, wave-uniform).
// Fused input rows r0..r0+4 staged in LDS (r0 = g*4).
extern "C" __global__ __launch_bounds__(NTH)
void structn_rows(const float* __restrict__ d,
                  const float* __restrict__ cd,
                  const float* __restrict__ gy,
                  const float* __restrict__ cgy,
                  const float* __restrict__ cc,
                  float* __restrict__ out)
{
    __shared__ float s_n[5 * W_];   // cgy_f * gy_f
    __shared__ float s_c[5 * W_];   // cgy_f

    const int g     = blockIdx.x;        // row group (44)
    const int plane = blockIdx.y;        // b*C + c  (64)
    const int c     = plane & (C_ - 1);

    const float* __restrict__ ch = cc + c * CSTRIDE;
    const float sw0 = ch[0], sw1 = ch[1], sw2 = ch[2];
    const float sw3 = ch[3], sw4 = ch[4], sw5 = ch[5];
    const float sw6 = ch[6], sw7 = ch[7], sw8 = ch[8];
    const float wp      = ch[9];
    const float inv_wp1 = ch[10];
    const float bv      = ch[11];
    const float icd_ee  = ch[12];
    const float icd_eo  = ch[13];
    const float icd_oe  = ch[14];
    const float icd_oo  = ch[15];

    const int r0  = g * 4;
    const int nrf = (r0 + 4 <= H_ - 1) ? 5 : (H_ - r0);   // 5, except last group 4

    const int pbase = plane * (H_ * W_);
    const float* __restrict__ dP  = d   + pbase;
    const float* __restrict__ cdP = cd  + pbase;
    const float* __restrict__ gyP = gy  + pbase;
    const float* __restrict__ cgP = cgy + pbase;

    // ---- stage fused rows r0..r0+nrf-1 (all float4, branchless wrap/zero) ----
    const int ntask = nrf * W4;
    for (int idx = threadIdx.x; idx < ntask; idx += NTH) {
        const int rf = idx / W4;
        const int iw = (idx - rf * W4) << 2;
        const int iy = r0 + rf;
        const int up = (iy == 0)      ? (H_ - 1) : iy - 1;   // d wraps (jnp.roll)
        const int dn = (iy == H_ - 1) ? 0        : iy + 1;
        const float mu = (iy > 0)      ? 1.0f : 0.0f;        // cd_up zeroed at row 0
        const float md = (iy < H_ - 1) ? 1.0f : 0.0f;        // cd_down zeroed at last

        const f4_t du = *(const f4_t*)(dP  + up * W_ + iw);
        const f4_t dd = *(const f4_t*)(dP  + dn * W_ + iw);
        const f4_t cu = *(const f4_t*)(cdP + up * W_ + iw);
        const f4_t cn = *(const f4_t*)(cdP + dn * W_ + iw);
        const f4_t gg = *(const f4_t*)(gyP + iy * W_ + iw);
        const f4_t cg = *(const f4_t*)(cgP + iy * W_ + iw);

        f4_t sn4, sc4;
#pragma unroll
        for (int e = 0; e < 4; ++e) {
            const float cuv = cu[e] * mu;
            const float cnv = cn[e] * md;
            const float cfd = cuv * cuv;
            const float rs  = __builtin_amdgcn_rcpf(fmaf(cuv, du[e], cnv * dd[e]));
            const float gfd = 0.5f * (dd[e] - du[e]) * (cuv + cnv) * rs;
            const float num = fmaf(wp * cg[e], gg[e], cfd * gfd);
            const float den = fmaf(wp, cg[e], cfd);
            sn4[e] = num * inv_wp1;
            sc4[e] = den * inv_wp1;
        }
        *(f4_t*)(s_n + rf * W_ + iw) = sn4;
        *(f4_t*)(s_c + rf * W_ + iw) = sc4;
    }
    __syncthreads();

    // ---- consume: wave w -> output row oy ----
    const int w    = threadIdx.x >> 6;
    const int lane = threadIdx.x & 63;
    const int oy   = g * 8 + w;
    if (oy >= HO_) return;

    const int p = w & 1;  // row parity, wave-uniform
    const int lrA = p ? ((w - 1) >> 1) : (w >> 1);
    const float* __restrict__ snA = s_n + lrA * W_;
    const float* __restrict__ scA = s_c + lrA * W_;
    const float* __restrict__ snB = p ? (snA + W_) : snA;  // row i+1 (odd rows)
    const float* __restrict__ scB = p ? (scA + W_) : scA;

    const int ro0 = plane * PLANE_O + oy * WO_;
    float* __restrict__ o0 = out + ro0;
    float* __restrict__ o1 = out + OUT1_O + ro0;

    const int h  = (4 - (ro0 & 3)) & 3;      // head scalars to reach 16B alignment
    const int n4 = (WO_ - h) >> 2;           // 303 aligned float4 chunks
    // head (h cols) + tail (3-h cols) = 3 leftover scalar columns
    if (lane < 3) {
        const int ox = (lane < h) ? lane : (h + (n4 << 2) + lane - h);
        const int q  = ox & 1;
        float den, nom, icd;
        if (p == 0) {
            if (q == 0) {
                const int j = ox >> 1;
                den = scA[j] * sw4;  nom = snA[j] * sw4;  icd = icd_ee;
            } else {
                const int j = (ox - 1) >> 1;
                den = scA[j] * sw5 + scA[j + 1] * sw3;
                nom = snA[j] * sw5 + snA[j + 1] * sw3;  icd = icd_eo;
            }
        } else {
            if (q == 0) {
                const int j = ox >> 1;
                den = scA[j] * sw7 + scB[j] * sw1;
                nom = snA[j] * sw7 + snB[j] * sw1;  icd = icd_oe;
            } else {
                const int j = (ox - 1) >> 1;
                den = scA[j] * sw8 + scA[j + 1] * sw6 + scB[j] * sw2 + scB[j + 1] * sw0;
                nom = snA[j] * sw8 + snA[j + 1] * sw6 + snB[j] * sw2 + snB[j + 1] * sw0;
                icd = icd_oo;
            }
        }
        o0[ox] = fmaf(0.5f * nom, __builtin_amdgcn_rcpf(den + EPS_), bv);
        o1[ox] = den * icd;
    }

    const int patB = h & 1;  // chunk col-parity pattern, wave-uniform
    if (p == 0) {
        if (!patB) {
            // cols: E(j0) O(j0) E(j0+1) O(j0+1)
            for (int k = lane; k < n4; k += 64) {
                const int c0 = h + (k << 2), j0 = c0 >> 1;
                const float a0 = snA[j0], a1 = snA[j0 + 1], a2 = snA[j0 + 2];
                const float x0 = scA[j0], x1 = scA[j0 + 1], x2 = scA[j0 + 2];
                const float d0 = x0 * sw4,            n0 = a0 * sw4;
                const float d1 = x0 * sw5 + x1 * sw3, n1 = a0 * sw5 + a1 * sw3;
                const float d2 = x1 * sw4,            n2 = a1 * sw4;
                const float d3 = x1 * sw5 + x2 * sw3, n3 = a1 * sw5 + a2 * sw3;
                f4_t gv, qv;
                gv.x = fmaf(0.5f * n0, __builtin_amdgcn_rcpf(d0 + EPS_), bv);
                gv.y = fmaf(0.5f * n1, __builtin_amdgcn_rcpf(d1 + EPS_), bv);
                gv.z = fmaf(0.5f * n2, __builtin_amdgcn_rcpf(d2 + EPS_), bv);
                gv.w = fmaf(0.5f * n3, __builtin_amdgcn_rcpf(d3 + EPS_), bv);
                qv.x = d0 * icd_ee; qv.y = d1 * icd_eo;
                qv.z = d2 * icd_ee; qv.w = d3 * icd_eo;
                *(f4_t*)(o0 + c0) = gv;
                *(f4_t*)(o1 + c0) = qv;
            }
        } else {
            // cols: O(j0) E(j0+1) O(j0+1) E(j0+2)
            for (int k = lane; k < n4; k += 64) {
                const int c0 = h + (k << 2), j0 = c0 >> 1;
                const float a0 = snA[j0], a1 = snA[j0 + 1], a2 = snA[j0 + 2];
                const float x0 = scA[j0], x1 = scA[j0 + 1], x2 = scA[j0 + 2];
                const float d0 = x0 * sw5 + x1 * sw3, n0 = a0 * sw5 + a1 * sw3;
                const float d1 = x1 * sw4,            n1 = a1 * sw4;
                const float d2 = x1 * sw5 + x2 * sw3, n2 = a1 * sw5 + a2 * sw3;
                const float d3 = x2 * sw4,            n3 = a2 * sw4;
                f4_t gv, qv;
                gv.x = fmaf(0.5f * n0, __builtin_amdgcn_rcpf(d0 + EPS_), bv);
                gv.y = fmaf(0.5f * n1, __builtin_amdgcn_rcpf(d1 + EPS_), bv);
                gv.z = fmaf(0.5f * n2, __builtin_amdgcn_rcpf(d2 + EPS_), bv);
                gv.w = fmaf(0.5f * n3, __builtin_amdgcn_rcpf(d3 + EPS_), bv);
                qv.x = d0 * icd_eo; qv.y = d1 * icd_ee;
                qv.z = d2 * icd_eo; qv.w = d3 * icd_ee;
                *(f4_t*)(o0 + c0) = gv;
                *(f4_t*)(o1 + c0) = qv;
            }
        }
    } else {
        if (!patB) {
            // cols: E(j0) O(j0) E(j0+1) O(j0+1); E: A*sw7+B*sw1, O: A[j]sw8+A[j+1]sw6+B[j]sw2+B[j+1]sw0
            for (int k = lane; k < n4; k += 64) {
                const int c0 = h + (k << 2), j0 = c0 >> 1;
                const float a0 = snA[j0], a1 = snA[j0 + 1], a2 = snA[j0 + 2];
                const float x0 = scA[j0], x1 = scA[j0 + 1], x2 = scA[j0 + 2];
                const float b0 = snB[j0], b1 = snB[j0 + 1], b2 = snB[j0 + 2];
                const float y0 = scB[j0], y1 = scB[j0 + 1], y2 = scB[j0 + 2];
                const float d0 = x0 * sw7 + y0 * sw1;
                const float n0 = a0 * sw7 + b0 * sw1;
                const float d1 = x0 * sw8 + x1 * sw6 + y0 * sw2 + y1 * sw0;
                const float n1 = a0 * sw8 + a1 * sw6 + b0 * sw2 + b1 * sw0;
                const float d2 = x1 * sw7 + y1 * sw1;
                const float n2 = a1 * sw7 + b1 * sw1;
                const float d3 = x1 * sw8 + x2 * sw6 + y1 * sw2 + y2 * sw0;
                const float n3 = a1 * sw8 + a2 * sw6 + b1 * sw2 + b2 * sw0;
                f4_t gv, qv;
                gv.x = fmaf(0.5f * n0, __builtin_amdgcn_rcpf(d0 + EPS_), bv);
                gv.y = fmaf(0.5f * n1, __builtin_amdgcn_rcpf(d1 + EPS_), bv);
                gv.z = fmaf(0.5f * n2, __builtin_amdgcn_rcpf(d2 + EPS_), bv);
                gv.w = fmaf(0.5f * n3, __builtin_amdgcn_rcpf(d3 + EPS_), bv);
                qv.x = d0 * icd_oe; qv.y = d1 * icd_oo;
                qv.z = d2 * icd_oe; qv.w = d3 * icd_oo;
                *(f4_t*)(o0 + c0) = gv;
                *(f4_t*)(o1 + c0) = qv;
            }
        } else {
            // cols: O(j0) E(j0+1) O(j0+1) E(j0+2)
            for (int k = lane; k < n4; k += 64) {
                const int c0 = h + (k << 2), j0 = c0 >> 1;
                const float a0 = snA[j0], a1 = snA[j0 + 1], a2 = snA[j0 + 2];
                const float x0 = scA[j0], x1 = scA[j0 + 1], x2 = scA[j0 + 2];
                const float b0 = snB[j0], b1 = snB[j0 + 1], b2 = snB[j0 + 2];
                const float y0 = scB[j0], y1 = scB[j0 + 1], y2 = scB[j0 + 2];
                const float d0 = x0 * sw8 + x1 * sw6 + y0 * sw2 + y1 * sw0;
                const float n0 = a0 * sw8 + a1 * sw6 + b0 * sw2 + b1 * sw0;
                const float d1 = x1 * sw7 + y1 * sw1;
                const float n1 = a1 * sw7 + b1 * sw1;
                const float d2 = x1 * sw8 + x2 * sw6 + y1 * sw2 + y2 * sw0;
                const float n2 = a1 * sw8 + a2 * sw6 + b1 * sw2 + b2 * sw0;
                const float d3 = x2 * sw7 + y2 * sw1;
                const float n3 = a2 * sw7 + b2 * sw1;
                f4_t gv, qv;
                gv.x = fmaf(0.5f * n0, __builtin_amdgcn_rcpf(d0 + EPS_), bv);
                gv.y = fmaf(0.5f * n1, __builtin_amdgcn_rcpf(d1 + EPS_), bv);
                gv.z = fmaf(0.5f * n2, __builtin_amdgcn_rcpf(d2 + EPS_), bv);
                gv.w = fmaf(0.5f * n3, __builtin_amdgcn_rcpf(d3 + EPS_), bv);
                qv.x = d0 * icd_oo; qv.y = d1 * icd_oe;
                qv.z = d2 * icd_oo; qv.w = d3 * icd_oe;
                *(f4_t*)(o0 + c0) = gv;
                *(f4_t*)(o1 + c0) = qv;
            }
        }
    }
}

extern "C" void kernel_launch(void* const* d_in, const int* in_sizes, int n_in,
                              void* d_out, int out_size, void* d_ws, size_t ws_size,
                              hipStream_t stream) {
    const float* d    = (const float*)d_in[0];
    const float* cd   = (const float*)d_in[1];
    const float* gy   = (const float*)d_in[2];
    const float* cgy  = (const float*)d_in[3];
    const float* wpr  = (const float*)d_in[4];
    const float* swr  = (const float*)d_in[5];
    const float* bias = (const float*)d_in[6];
    float* out = (float*)d_out;
    float* cc  = (float*)d_ws;   // 2 KiB scratch

    precompute_consts<<<1, 64, 0, stream>>>(wpr, swr, bias, cc);

    dim3 grid(44, B_ * C_);      // 44 row-groups x 64 planes
    structn_rows<<<grid, NTH, 0, stream>>>(d, cd, gy, cgy, cc, out);
}

// Round 6
// 73.813 us; speedup vs baseline: 1.7332x; 1.1620x over previous
//
#include <hip/hip_runtime.h>
#include <math.h>

// Problem constants
#define B_   2
#define C_   32
#define H_   176
#define W_   608
#define HO_  351
#define WO_  1215
#define PLANE_O (HO_ * WO_)          // 426465
#define OUT1_O  (B_ * C_ * PLANE_O)  // 27293760 (mult of 4 -> same alignment)
#define EPS_ 1e-20f
#define NTH  512
#define W4   (W_ / 4)                // 152 float4 per input row
#define HW_  304                     // half-row length (col-parity split)

typedef float f4_t __attribute__((ext_vector_type(4)));
typedef float f2_t __attribute__((ext_vector_type(2)));

__device__ __forceinline__ float softplus_f(float x) {
    return fmaxf(x, 0.0f) + log1pf(expf(-fabsf(x)));
}

// Block = (row-group g, plane). 8 waves; wave w owns output row oy = g*8+w.
// Fused input rows r0..r0+4 staged in LDS, split by column parity so the
// consume phase reads are stride-1 (conflict-free).
extern "C" __global__ __launch_bounds__(NTH, 8)
void structn_rows(const float* __restrict__ d,
                  const float* __restrict__ cd,
                  const float* __restrict__ gy,
                  const float* __restrict__ cgy,
                  const float* __restrict__ wpr,
                  const float* __restrict__ swr,
                  const float* __restrict__ bias,
                  float* __restrict__ out)
{
    __shared__ float s_nE[5 * HW_];   // cgy_f*gy_f, even input cols
    __shared__ float s_nO[5 * HW_];   // cgy_f*gy_f, odd input cols
    __shared__ float s_cE[5 * HW_];   // cgy_f, even cols
    __shared__ float s_cO[5 * HW_];   // cgy_f, odd cols

    const int g     = blockIdx.x;     // 44 row groups
    const int plane = blockIdx.y;     // 64 planes
    const int c     = plane & (C_ - 1);

    // ---- per-channel constants, computed in-block (wave-uniform) ----
    float sw[9];
#pragma unroll
    for (int k = 0; k < 9; ++k) sw[k] = softplus_f(swr[c * 9 + k]);
    const float wp      = softplus_f(wpr[c]);
    const float inv_wp1 = 1.0f / (wp + 1.0f);
    const float bv      = bias[c];
    const float icd_ee  = 1.0f / (sw[4] + EPS_);
    const float icd_eo  = 1.0f / (sw[3] + sw[5] + EPS_);
    const float icd_oe  = 1.0f / (sw[1] + sw[7] + EPS_);
    const float icd_oo  = 1.0f / (sw[0] + sw[2] + sw[6] + sw[8] + EPS_);

    const int r0  = g * 4;
    const int nrf = (r0 + 4 <= H_ - 1) ? 5 : (H_ - r0);

    const int pbase = plane * (H_ * W_);
    const float* __restrict__ dP  = d   + pbase;
    const float* __restrict__ cdP = cd  + pbase;
    const float* __restrict__ gyP = gy  + pbase;
    const float* __restrict__ cgP = cgy + pbase;

    // ---- stage fused rows (float4 loads, branchless wrap/zero, split write) ----
    const int ntask = nrf * W4;
    for (int idx = threadIdx.x; idx < ntask; idx += NTH) {
        const int rf = idx / W4;
        const int iw = (idx - rf * W4) << 2;
        const int iy = r0 + rf;
        const int up = (iy == 0)      ? (H_ - 1) : iy - 1;   // d wraps (jnp.roll)
        const int dn = (iy == H_ - 1) ? 0        : iy + 1;
        const float mu = (iy > 0)      ? 1.0f : 0.0f;
        const float md = (iy < H_ - 1) ? 1.0f : 0.0f;

        const f4_t du = *(const f4_t*)(dP  + up * W_ + iw);
        const f4_t dd = *(const f4_t*)(dP  + dn * W_ + iw);
        const f4_t cu = *(const f4_t*)(cdP + up * W_ + iw);
        const f4_t cn = *(const f4_t*)(cdP + dn * W_ + iw);
        const f4_t gg = *(const f4_t*)(gyP + iy * W_ + iw);
        const f4_t cg = *(const f4_t*)(cgP + iy * W_ + iw);

        f4_t sn4, sc4;
#pragma unroll
        for (int e = 0; e < 4; ++e) {
            const float cuv = cu[e] * mu;
            const float cnv = cn[e] * md;
            const float cfd = cuv * cuv;
            const float rs  = __builtin_amdgcn_rcpf(fmaf(cuv, du[e], cnv * dd[e]));
            const float gfd = 0.5f * (dd[e] - du[e]) * (cuv + cnv) * rs;
            const float num = fmaf(wp * cg[e], gg[e], cfd * gfd);
            const float den = fmaf(wp, cg[e], cfd);
            sn4[e] = num * inv_wp1;
            sc4[e] = den * inv_wp1;
        }
        const int eo = rf * HW_ + (iw >> 1);    // iw mult of 4 -> eo even -> 8B aligned
        f2_t v;
        v[0] = sn4[0]; v[1] = sn4[2];  *(f2_t*)(s_nE + eo) = v;
        v[0] = sn4[1]; v[1] = sn4[3];  *(f2_t*)(s_nO + eo) = v;
        v[0] = sc4[0]; v[1] = sc4[2];  *(f2_t*)(s_cE + eo) = v;
        v[0] = sc4[1]; v[1] = sc4[3];  *(f2_t*)(s_cO + eo) = v;
    }
    __syncthreads();

    // ---- consume: wave w -> output row oy = g*8+w ----
    const int w    = threadIdx.x >> 6;
    const int lane = threadIdx.x & 63;
    const int oy   = g * 8 + w;
    if (oy >= HO_) return;

    const int p   = w & 1;       // output-row parity (wave-uniform)
    const int lrA = w >> 1;      // local fused row i

    const int ro0 = plane * PLANE_O + oy * WO_;
    float* __restrict__ o0 = out + ro0;
    float* __restrict__ o1 = out + OUT1_O + ro0;

    const int h  = (4 - (ro0 & 3)) & 3;   // head scalars to 16B alignment
    const int n4 = (WO_ - h) >> 2;        // = 303 aligned float4 chunks
    const int q  = h & 1;                 // chunk col parity
    const int r  = (h >> 1) & 1;          // j0 parity (j0 = (h>>1) + 2k)

    // icd pattern per chunk position
    const float icdC = p ? icd_oe : icd_ee;
    const float icdO = p ? icd_oo : icd_eo;
    const float i0 = q ? icdO : icdC;
    const float i1 = q ? icdC : icdO;

    const float* __restrict__ nAE = s_nE + lrA * HW_;
    const float* __restrict__ nAO = s_nO + lrA * HW_;
    const float* __restrict__ cAE = s_cE + lrA * HW_;
    const float* __restrict__ cAO = s_cO + lrA * HW_;

#define VAL(E, O, j) (((j) & 1) ? (O)[((j) - 1) >> 1] : (E)[(j) >> 1])

    if (p == 0) {
        // Even row: C(j) = v[j]*sw4 ; Off(j) = v[j]*sw5 + v[j+1]*sw3
        // leftover scalar columns (3 of them)
        if (lane < 3) {
            const int ox = (lane < h) ? lane : (h + (n4 << 2) + lane - h);
            float den, nom, icd;
            if ((ox & 1) == 0) {
                const int j = ox >> 1;
                den = VAL(cAE, cAO, j) * sw[4];
                nom = VAL(nAE, nAO, j) * sw[4];
                icd = icd_ee;
            } else {
                const int j = (ox - 1) >> 1;
                den = VAL(cAE, cAO, j) * sw[5] + VAL(cAE, cAO, j + 1) * sw[3];
                nom = VAL(nAE, nAO, j) * sw[5] + VAL(nAE, nAO, j + 1) * sw[3];
                icd = icd_eo;
            }
            o0[ox] = fmaf(0.5f * nom, __builtin_amdgcn_rcpf(den + EPS_), bv);
            o1[ox] = den * icd;
        }
        // stride-1 pointer trios: r=0 -> (E,O,E+1); r=1 -> (O,E+1,O+1)
        const float* pa0 = r ? nAO : nAE;
        const float* pa1 = r ? nAE + 1 : nAO;
        const float* pa2 = r ? nAO + 1 : nAE + 1;
        const float* px0 = r ? cAO : cAE;
        const float* px1 = r ? cAE + 1 : cAO;
        const float* px2 = r ? cAO + 1 : cAE + 1;

        for (int k = lane; k < n4; k += 64) {
            const float a0 = pa0[k], a1 = pa1[k], a2 = pa2[k];
            const float x0 = px0[k], x1 = px1[k], x2 = px2[k];
            const float dC0 = x0 * sw[4], dC1 = x1 * sw[4], dC2 = x2 * sw[4];
            const float nC0 = a0 * sw[4], nC1 = a1 * sw[4], nC2 = a2 * sw[4];
            const float dF0 = x0 * sw[5] + x1 * sw[3];
            const float dF1 = x1 * sw[5] + x2 * sw[3];
            const float nF0 = a0 * sw[5] + a1 * sw[3];
            const float nF1 = a1 * sw[5] + a2 * sw[3];

            const float d0 = q ? dF0 : dC0, n0 = q ? nF0 : nC0;
            const float d1 = q ? dC1 : dF0, n1 = q ? nC1 : nF0;
            const float d2 = q ? dF1 : dC1, n2 = q ? nF1 : nC1;
            const float d3 = q ? dC2 : dF1, n3 = q ? nC2 : nF1;

            f4_t gv, qv;
            gv[0] = fmaf(0.5f * n0, __builtin_amdgcn_rcpf(d0 + EPS_), bv);
            gv[1] = fmaf(0.5f * n1, __builtin_amdgcn_rcpf(d1 + EPS_), bv);
            gv[2] = fmaf(0.5f * n2, __builtin_amdgcn_rcpf(d2 + EPS_), bv);
            gv[3] = fmaf(0.5f * n3, __builtin_amdgcn_rcpf(d3 + EPS_), bv);
            qv[0] = d0 * i0; qv[1] = d1 * i1; qv[2] = d2 * i0; qv[3] = d3 * i1;

            const int c0 = h + (k << 2);
            __builtin_nontemporal_store(gv, (f4_t*)(o0 + c0));
            __builtin_nontemporal_store(qv, (f4_t*)(o1 + c0));
        }
    } else {
        // Odd row: uses rows i (A) and i+1 (B).
        // C(j) = xA[j]*sw7 + xB[j]*sw1 ; Off(j) = xA[j]*sw8+xA[j+1]*sw6+xB[j]*sw2+xB[j+1]*sw0
        const float* __restrict__ nBE = nAE + HW_;
        const float* __restrict__ nBO = nAO + HW_;
        const float* __restrict__ cBE = cAE + HW_;
        const float* __restrict__ cBO = cAO + HW_;

        if (lane < 3) {
            const int ox = (lane < h) ? lane : (h + (n4 << 2) + lane - h);
            float den, nom, icd;
            if ((ox & 1) == 0) {
                const int j = ox >> 1;
                den = VAL(cAE, cAO, j) * sw[7] + VAL(cBE, cBO, j) * sw[1];
                nom = VAL(nAE, nAO, j) * sw[7] + VAL(nBE, nBO, j) * sw[1];
                icd = icd_oe;
            } else {
                const int j = (ox - 1) >> 1;
                den = VAL(cAE, cAO, j) * sw[8] + VAL(cAE, cAO, j + 1) * sw[6]
                    + VAL(cBE, cBO, j) * sw[2] + VAL(cBE, cBO, j + 1) * sw[0];
                nom = VAL(nAE, nAO, j) * sw[8] + VAL(nAE, nAO, j + 1) * sw[6]
                    + VAL(nBE, nBO, j) * sw[2] + VAL(nBE, nBO, j + 1) * sw[0];
                icd = icd_oo;
            }
            o0[ox] = fmaf(0.5f * nom, __builtin_amdgcn_rcpf(den + EPS_), bv);
            o1[ox] = den * icd;
        }

        const float* pa0 = r ? nAO : nAE;
        const float* pa1 = r ? nAE + 1 : nAO;
        const float* pa2 = r ? nAO + 1 : nAE + 1;
        const float* px0 = r ? cAO : cAE;
        const float* px1 = r ? cAE + 1 : cAO;
        const float* px2 = r ? cAO + 1 : cAE + 1;
        const float* pb0 = r ? nBO : nBE;
        const float* pb1 = r ? nBE + 1 : nBO;
        const float* pb2 = r ? nBO + 1 : nBE + 1;
        const float* py0 = r ? cBO : cBE;
        const float* py1 = r ? cBE + 1 : cBO;
        const float* py2 = r ? cBO + 1 : cBE + 1;

        for (int k = lane; k < n4; k += 64) {
            const float a0 = pa0[k], a1 = pa1[k], a2 = pa2[k];
            const float x0 = px0[k], x1 = px1[k], x2 = px2[k];
            const float b0 = pb0[k], b1 = pb1[k], b2 = pb2[k];
            const float y0 = py0[k], y1 = py1[k], y2 = py2[k];

            const float dC0 = x0 * sw[7] + y0 * sw[1];
            const float dC1 = x1 * sw[7] + y1 * sw[1];
            const float dC2 = x2 * sw[7] + y2 * sw[1];
            const float nC0 = a0 * sw[7] + b0 * sw[1];
            const float nC1 = a1 * sw[7] + b1 * sw[1];
            const float nC2 = a2 * sw[7] + b2 * sw[1];
            const float dF0 = x0 * sw[8] + x1 * sw[6] + y0 * sw[2] + y1 * sw[0];
            const float dF1 = x1 * sw[8] + x2 * sw[6] + y1 * sw[2] + y2 * sw[0];
            const float nF0 = a0 * sw[8] + a1 * sw[6] + b0 * sw[2] + b1 * sw[0];
            const float nF1 = a1 * sw[8] + a2 * sw[6] + b1 * sw[2] + b2 * sw[0];

            const float d0 = q ? dF0 : dC0, n0 = q ? nF0 : nC0;
            const float d1 = q ? dC1 : dF0, n1 = q ? nC1 : nF0;
            const float d2 = q ? dF1 : dC1, n2 = q ? nF1 : nC1;
            const float d3 = q ? dC2 : dF1, n3 = q ? nC2 : nF1;

            f4_t gv, qv;
            gv[0] = fmaf(0.5f * n0, __builtin_amdgcn_rcpf(d0 + EPS_), bv);
            gv[1] = fmaf(0.5f * n1, __builtin_amdgcn_rcpf(d1 + EPS_), bv);
            gv[2] = fmaf(0.5f * n2, __builtin_amdgcn_rcpf(d2 + EPS_), bv);
            gv[3] = fmaf(0.5f * n3, __builtin_amdgcn_rcpf(d3 + EPS_), bv);
            qv[0] = d0 * i0; qv[1] = d1 * i1; qv[2] = d2 * i0; qv[3] = d3 * i1;

            const int c0 = h + (k << 2);
            __builtin_nontemporal_store(gv, (f4_t*)(o0 + c0));
            __builtin_nontemporal_store(qv, (f4_t*)(o1 + c0));
        }
    }
#undef VAL
}

extern "C" void kernel_launch(void* const* d_in, const int* in_sizes, int n_in,
                              void* d_out, int out_size, void* d_ws, size_t ws_size,
                              hipStream_t stream) {
    const float* d    = (const float*)d_in[0];
    const float* cd   = (const float*)d_in[1];
    const float* gy   = (const float*)d_in[2];
    const float* cgy  = (const float*)d_in[3];
    const float* wpr  = (const float*)d_in[4];
    const float* swr  = (const float*)d_in[5];
    const float* bias = (const float*)d_in[6];
    float* out = (float*)d_out;

    dim3 grid(44, B_ * C_);
    structn_rows<<<grid, NTH, 0, stream>>>(d, cd, gy, cgy, wpr, swr, bias, out);
}